// Round 9
// baseline (104.422 us; speedup 1.0000x reference)
//
#include <hip/hip_runtime.h>
#include <hip/hip_bf16.h>

// Problem constants
#define Bq   4
#define Cc   64
#define Hh   160
#define Ww   160
#define HWp  (Hh * Ww)          // 25600
#define COUTc 64

typedef __attribute__((ext_vector_type(8))) short bf16x8;
typedef __attribute__((ext_vector_type(4))) float f32x4;
typedef __attribute__((ext_vector_type(2))) float f32x2;
typedef __attribute__((ext_vector_type(4))) int   int4v;

// ws layout (shorts):
//   wTbF  : 72 frags x 512 shorts  (main weights, fragment-major)
//           frag fidx = (tap*2+h)*4 + cg ; element l*8+j =
//           w[o=cg*16+(l&15)][c=h*32+(l>>4)*8+j][tap]
//   wToffF: 36 frags x 512 shorts  (offset weights, fragment-major)
//           frag fidx = (tap*2+h)*2 + g ; element l*8+j =
//           w_off[oc=g*16+(l&15)][c][tap]  (oc>=18 -> 0)
//   xcl   [b][y][x][c] : 4*25600*64 + 64 (zero pad pixel at end)
#define WTBF_SHORTS   (72 * 512)                    // 36864
#define WTOFFF_SHORTS (36 * 512)                    // 18432
#define XCL_OFS       (WTBF_SHORTS + WTOFFF_SHORTS) // 55296
#define XCL_PIX       ((size_t)Bq * HWp)            // zero pad pixel index
#define XCL_SHORTS    (XCL_PIX * 64 + 64)

__device__ __forceinline__ short f2bf(float f) {
    union { float f; unsigned u; } v; v.f = f;
    unsigned r = v.u + 0x7fffu + ((v.u >> 16) & 1u);   // RNE
    return (short)(r >> 16);
}
__device__ __forceinline__ float bflo(unsigned u) {
    union { unsigned u; float f; } v; v.u = u << 16; return v.f;
}
__device__ __forceinline__ float bfhi(unsigned u) {
    union { unsigned u; float f; } v; v.u = u & 0xffff0000u; return v.f;
}
__device__ __forceinline__ unsigned pk2(float lo, float hi) {
    union { __hip_bfloat162 h; unsigned u; } v;
    v.h = __float22bfloat162_rn(float2{lo, hi});       // v_cvt_pk_bf16_f32
    return v.u;
}

// ---------------------------------------------------------------------------
// Merged prep: [0,400) xcl image; [400,544) fragment-major weights; 544 pad.
// (unchanged from round 8 — layouts identical, already validated)
// ---------------------------------------------------------------------------
__global__ __launch_bounds__(256) void prep_all(const float* __restrict__ x,
                                                const float* __restrict__ w,
                                                const float* __restrict__ w_off,
                                                short* __restrict__ ws) {
    int blk = blockIdx.x;
    int tid = threadIdx.x;
    if (blk < 400) {
        int g = blk * 256 + tid;             // pixel id
        int b = g / HWp, p = g - b * HWp;
        const float* xp = x + (size_t)b * Cc * HWp + p;
        short* op = ws + XCL_OFS + (size_t)g * 64;
#pragma unroll
        for (int cg = 0; cg < 8; ++cg) {
            unsigned d[4];
#pragma unroll
            for (int dj = 0; dj < 4; ++dj) {
                float f0 = xp[(size_t)(cg * 8 + 2 * dj) * HWp];
                float f1 = xp[(size_t)(cg * 8 + 2 * dj + 1) * HWp];
                d[dj] = pk2(f0, f1);
            }
            *(int4v*)(op + cg * 8) = *(int4v*)d;
        }
    } else if (blk < 544) {
        int i = (blk - 400) * 256 + tid;
        if (i < WTBF_SHORTS) {
            int fidx = i >> 9, r = i & 511;
            int l = r >> 3, j = r & 7;
            int cg = fidx & 3, th = fidx >> 2;
            int tap = th >> 1, h = th & 1;
            int o = cg * 16 + (l & 15);
            int c = h * 32 + ((l >> 4) << 3) + j;
            ws[i] = f2bf(w[o * 576 + c * 9 + tap]);
        }
        if (i < WTOFFF_SHORTS) {
            int fidx = i >> 9, r = i & 511;
            int l = r >> 3, j = r & 7;
            int g = fidx & 1, th = fidx >> 1;
            int tap = th >> 1, h = th & 1;
            int oc = g * 16 + (l & 15);
            int c = h * 32 + ((l >> 4) << 3) + j;
            float v = (oc < 18) ? w_off[oc * 576 + c * 9 + tap] : 0.f;
            ws[WTBF_SHORTS + i] = f2bf(v);
        }
    } else {
        if (tid < 8)
            *(int4v*)((char*)(ws + XCL_OFS) + XCL_PIX * 128 + tid * 16) =
                (int4v){0, 0, 0, 0};
    }
}

// ---------------------------------------------------------------------------
// Bilinear combine: 4 corner bf16x8 fragments -> one bf16x8 A-fragment.
// ---------------------------------------------------------------------------
__device__ __forceinline__ bf16x8 bil4(bf16x8 c0, bf16x8 c1, bf16x8 c2,
                                       bf16x8 c3, f32x4 wg) {
    union { bf16x8 v; unsigned u[4]; } U0, U1, U2, U3;
    U0.v = c0; U1.v = c1; U2.v = c2; U3.v = c3;
    union { unsigned u[4]; bf16x8 v; } A;
#pragma unroll
    for (int d = 0; d < 4; ++d) {
        f32x2 v0 = {bflo(U0.u[d]), bfhi(U0.u[d])};
        f32x2 v1 = {bflo(U1.u[d]), bfhi(U1.u[d])};
        f32x2 v2 = {bflo(U2.u[d]), bfhi(U2.u[d])};
        f32x2 v3 = {bflo(U3.u[d]), bfhi(U3.u[d])};
        f32x2 s = v0 * wg[0] + v1 * wg[1] + v2 * wg[2] + v3 * wg[3];
        A.u[d] = pk2(s[0], s[1]);
    }
    return A.v;
}

// ---------------------------------------------------------------------------
// Fused kernel, barrier-free: 4 independent waves/block, 16 px each, N=64.
// A-fragments built entirely in registers (lane = (row, kslice) of MFMA A).
// ---------------------------------------------------------------------------
__global__ __launch_bounds__(256, 4) void fused_cl(const short* __restrict__ ws,
                                                   const float* __restrict__ b_off,
                                                   const float* __restrict__ bias,
                                                   float* __restrict__ out) {
    __shared__ float offbuf[4][16][20];   // wave-private slices
    __shared__ int4v linT[4][16][9];
    __shared__ f32x4 wgtT[4][16][9];

    int tid = threadIdx.x;
    int wid = tid >> 6;
    int l   = tid & 63;
    int lr  = l & 15;      // MFMA row lane (= pixel within wave tile)
    int lg  = l >> 4;      // k-slice group

    // XCD-aware swizzle: nwg = 1600, 1600 % 8 == 0 -> bijective
    int bid = blockIdx.x;
    int g_blk = (bid & 7) * 200 + (bid >> 3);

    int gpix = g_blk * 64 + wid * 16;     // wave's 16-px tile, row-aligned
    int b   = gpix / HWp;
    int rem = gpix - b * HWp;
    int y   = rem / Ww;                   // wave-uniform (16 | 160)
    int x0  = rem - y * Ww;

    const short* wTbF   = ws;
    const short* wToffF = ws + WTBF_SHORTS;
    const char*  xclb   = (const char*)(ws + XCL_OFS) + (size_t)b * HWp * 128;
    const int zoff = (int)((Bq - b) * (size_t)HWp * 128);   // zero pad pixel

    // ---------------- Phase 1: offset GEMM (M=16, N=32, 4-deep) -----------
    {
        int xpix = x0 + lr;
        int poff[9];
#pragma unroll
        for (int ty = 0; ty < 3; ++ty) {
#pragma unroll
            for (int tx = 0; tx < 3; ++tx) {
                int t  = ty * 3 + tx;
                int yy = y - 1 + ty;
                bool vy = (yy >= 0) && (yy < Hh);
                int yc = min(max(yy, 0), Hh - 1);
                int xx = xpix - 1 + tx;
                bool vx = (xx >= 0) && (xx < Ww);
                int xc = min(max(xx, 0), Ww - 1);
                poff[t] = (vy && vx) ? (yc * Ww + xc) * 128 : zoff;
            }
        }
        const short* wofr = wToffF + l * 8;
        f32x4 accO0 = {0.f, 0.f, 0.f, 0.f};
        f32x4 accO1 = {0.f, 0.f, 0.f, 0.f};
        bf16x8 sA[4], sB0[4], sB1[4];
#pragma unroll
        for (int u = 0; u < 4; ++u) {
            const int t = u >> 1, h = u & 1;
            sA[u]  = *(const bf16x8*)(xclb + poff[t] + h * 64 + lg * 16);
            sB0[u] = *(const bf16x8*)(wofr + u * 1024);
            sB1[u] = *(const bf16x8*)(wofr + u * 1024 + 512);
        }
#pragma unroll
        for (int u = 0; u < 18; ++u) {
            const int s = u & 3;
            accO0 = __builtin_amdgcn_mfma_f32_16x16x32_bf16(sA[s], sB0[s], accO0, 0, 0, 0);
            accO1 = __builtin_amdgcn_mfma_f32_16x16x32_bf16(sA[s], sB1[s], accO1, 0, 0, 0);
            if (u + 4 < 18) {
                const int un = u + 4, t = un >> 1, h = un & 1;
                sA[s]  = *(const bf16x8*)(xclb + poff[t] + h * 64 + lg * 16);
                sB0[s] = *(const bf16x8*)(wofr + un * 1024);
                sB1[s] = *(const bf16x8*)(wofr + un * 1024 + 512);
            }
            __builtin_amdgcn_sched_barrier(0);
        }
        // C layout: col = lr (= offset channel), row = lg*4+j (= pixel)
        float bv0 = b_off[lr];
#pragma unroll
        for (int j = 0; j < 4; ++j)
            offbuf[wid][lg * 4 + j][lr] = accO0[j] + bv0;
        if (lr < 2) {
            float bv1 = b_off[16 + lr];
#pragma unroll
            for (int j = 0; j < 4; ++j)
                offbuf[wid][lg * 4 + j][16 + lr] = accO1[j] + bv1;
        }
    }
    // wave-internal LDS fence (no __syncthreads: slices are wave-private)
    asm volatile("s_waitcnt lgkmcnt(0)" ::: "memory");
    __builtin_amdgcn_sched_barrier(0);

    // ---------------- Phase 2: bilinear tables (144 over 64 lanes) --------
    for (int i = l; i < 144; i += 64) {
        int px = i / 9, tap = i - px * 9;
        int ty = tap / 3, tx = tap - ty * 3;
        f32x2 d2 = *(const f32x2*)&offbuf[wid][px][2 * tap];
        float py  = (float)(y - 1 + ty) + d2[0];
        float pxf = (float)(x0 + px - 1 + tx) + d2[1];
        float fy = floorf(py), fx = floorf(pxf);
        float ly = py - fy, lx = pxf - fx;
        int iy0 = (int)fy, ix0 = (int)fx;
        int iy1 = iy0 + 1, ix1 = ix0 + 1;
        bool vy0 = (iy0 >= 0) && (iy0 < Hh);
        bool vy1 = (iy1 >= 0) && (iy1 < Hh);
        bool vx0 = (ix0 >= 0) && (ix0 < Ww);
        bool vx1 = (ix1 >= 0) && (ix1 < Ww);
        int cy0 = min(max(iy0, 0), Hh - 1), cy1 = min(max(iy1, 0), Hh - 1);
        int cx0 = min(max(ix0, 0), Ww - 1), cx1 = min(max(ix1, 0), Ww - 1);
        int4v li; f32x4 wg;
        li[0] = (cy0 * Ww + cx0) * 128;  wg[0] = (vy0 && vx0) ? (1.f - ly) * (1.f - lx) : 0.f;
        li[1] = (cy0 * Ww + cx1) * 128;  wg[1] = (vy0 && vx1) ? (1.f - ly) * lx         : 0.f;
        li[2] = (cy1 * Ww + cx0) * 128;  wg[2] = (vy1 && vx0) ? ly * (1.f - lx)         : 0.f;
        li[3] = (cy1 * Ww + cx1) * 128;  wg[3] = (vy1 && vx1) ? ly * lx                 : 0.f;
        linT[wid][px][tap] = li;
        wgtT[wid][px][tap] = wg;
    }
    asm volatile("s_waitcnt lgkmcnt(0)" ::: "memory");
    __builtin_amdgcn_sched_barrier(0);

    // ---------------- Phase 3: main GEMM, in-register A ----------
    f32x4 acc[4];
#pragma unroll
    for (int cg = 0; cg < 4; ++cg) acc[cg] = (f32x4){0.f, 0.f, 0.f, 0.f};

    const short* wfb = wTbF + l * 8;
    const int cb = lg * 16;
    bf16x8 cs[2][8];   // [slot][corner*2 + h] corner staging, 1 tap ahead
    {
        int4v li = linT[wid][lr][0];
#pragma unroll
        for (int c = 0; c < 4; ++c) {
            const char* q = xclb + li[c] + cb;
            cs[0][2 * c]     = *(const bf16x8*)(q);
            cs[0][2 * c + 1] = *(const bf16x8*)(q + 64);
        }
    }
#pragma unroll
    for (int t = 0; t < 9; ++t) {
        if (t < 8) {
            int4v li = linT[wid][lr][t + 1];
            const int ns = (t + 1) & 1;
#pragma unroll
            for (int c = 0; c < 4; ++c) {
                const char* q = xclb + li[c] + cb;
                cs[ns][2 * c]     = *(const bf16x8*)(q);
                cs[ns][2 * c + 1] = *(const bf16x8*)(q + 64);
            }
        }
        __builtin_amdgcn_sched_barrier(0);
        const int s = t & 1;
        f32x4 wg = wgtT[wid][lr][t];
        // h = 0 : B loads issued first, latency hidden under bilinear VALU
        {
            bf16x8 b0[4];
#pragma unroll
            for (int cg = 0; cg < 4; ++cg)
                b0[cg] = *(const bf16x8*)(wfb + ((t * 2 + 0) * 4 + cg) * 512);
            bf16x8 a0 = bil4(cs[s][0], cs[s][2], cs[s][4], cs[s][6], wg);
#pragma unroll
            for (int cg = 0; cg < 4; ++cg)
                acc[cg] = __builtin_amdgcn_mfma_f32_16x16x32_bf16(a0, b0[cg], acc[cg], 0, 0, 0);
        }
        // h = 1
        {
            bf16x8 b1[4];
#pragma unroll
            for (int cg = 0; cg < 4; ++cg)
                b1[cg] = *(const bf16x8*)(wfb + ((t * 2 + 1) * 4 + cg) * 512);
            bf16x8 a1 = bil4(cs[s][1], cs[s][3], cs[s][5], cs[s][7], wg);
#pragma unroll
            for (int cg = 0; cg < 4; ++cg)
                acc[cg] = __builtin_amdgcn_mfma_f32_16x16x32_bf16(a1, b1[cg], acc[cg], 0, 0, 0);
        }
    }

    // ---------------- Epilogue ----------------
    float* obase = out + (size_t)b * COUTc * HWp + y * Ww + x0;
#pragma unroll
    for (int cg = 0; cg < 4; ++cg) {
        int o = cg * 16 + lr;
        float bv = bias[o];
#pragma unroll
        for (int j = 0; j < 4; ++j)
            obase[(size_t)o * HWp + lg * 4 + j] = acc[cg][j] + bv;
    }
}

// ---------------------------------------------------------------------------
extern "C" void kernel_launch(void* const* d_in, const int* in_sizes, int n_in,
                              void* d_out, int out_size, void* d_ws, size_t ws_size,
                              hipStream_t stream) {
    const float* x      = (const float*)d_in[0];
    const float* w_off  = (const float*)d_in[1];
    const float* b_off  = (const float*)d_in[2];
    const float* weight = (const float*)d_in[3];
    const float* bias   = (const float*)d_in[4];
    float* outp = (float*)d_out;
    short* ws   = (short*)d_ws;

    // 400 blocks xcl + 144 blocks weights + 1 block zero pad
    prep_all<<<545, 256, 0, stream>>>(x, weight, w_off, ws);

    int nblocks = (Bq * HWp) / 64;   // 1600 workgroups, 4 waves x 16 px
    fused_cl<<<nblocks, 256, 0, stream>>>(ws, b_off, bias, outp);
}

// Round 10
// 79.519 us; speedup vs baseline: 1.3132x; 1.3132x over previous
//
#include <hip/hip_runtime.h>
#include <hip/hip_bf16.h>

// Problem constants
#define Bq   4
#define Cc   64
#define Hh   160
#define Ww   160
#define HWp  (Hh * Ww)          // 25600
#define COUTc 64

typedef __attribute__((ext_vector_type(8))) _Float16 f16x8;
typedef __attribute__((ext_vector_type(4))) _Float16 f16x4;
typedef __attribute__((ext_vector_type(4))) float f32x4;
typedef __attribute__((ext_vector_type(2))) float f32x2;
typedef __attribute__((ext_vector_type(4))) int   int4v;

// ws layout (shorts, fp16 bit patterns):
//   wTbF  : 72 frags x 512  (main weights, fragment-major)
//           frag fidx = (tap*2+h)*4 + cg ; element l*8+j =
//           w[o=cg*16+(l&15)][c=h*32+(l>>4)*8+j][tap]
//   wToffF: 36 frags x 512  (offset weights, fragment-major)
//           frag fidx = (tap*2+h)*2 + g ; element l*8+j =
//           w_off[oc=g*16+(l&15)][c][tap]  (oc>=18 -> 0)
//   xcl   [b][y][x][c] : 4*25600*64 + 64 (zero pad pixel at end)
#define WTBF_SHORTS   (72 * 512)                    // 36864
#define WTOFFF_SHORTS (36 * 512)                    // 18432
#define XCL_OFS       (WTBF_SHORTS + WTOFFF_SHORTS) // 55296
#define XCL_PIX       ((size_t)Bq * HWp)            // zero pad pixel index
#define XCL_SHORTS    (XCL_PIX * 64 + 64)

__device__ __forceinline__ short f2h(float f) {
    union { _Float16 h; short s; } v; v.h = (_Float16)f; return v.s;
}
__device__ __forceinline__ unsigned pk2h(float a, float b) {
    union { _Float16 h[2]; unsigned u; } v;
    v.h[0] = (_Float16)a; v.h[1] = (_Float16)b; return v.u;
}
__device__ __forceinline__ f16x8 vsplat(_Float16 v) {
    return (f16x8){v, v, v, v, v, v, v, v};
}

// ---------------------------------------------------------------------------
// Merged prep: [0,400) xcl image (fp16); [400,544) fragment-major weights;
// 544 zero pad.
// ---------------------------------------------------------------------------
__global__ __launch_bounds__(256) void prep_all(const float* __restrict__ x,
                                                const float* __restrict__ w,
                                                const float* __restrict__ w_off,
                                                short* __restrict__ ws) {
    int blk = blockIdx.x;
    int tid = threadIdx.x;
    if (blk < 400) {
        int g = blk * 256 + tid;             // pixel id
        int b = g / HWp, p = g - b * HWp;
        const float* xp = x + (size_t)b * Cc * HWp + p;
        short* op = ws + XCL_OFS + (size_t)g * 64;
#pragma unroll
        for (int cg = 0; cg < 8; ++cg) {
            unsigned d[4];
#pragma unroll
            for (int dj = 0; dj < 4; ++dj) {
                float f0 = xp[(size_t)(cg * 8 + 2 * dj) * HWp];
                float f1 = xp[(size_t)(cg * 8 + 2 * dj + 1) * HWp];
                d[dj] = pk2h(f0, f1);
            }
            *(int4v*)(op + cg * 8) = *(int4v*)d;
        }
    } else if (blk < 544) {
        int i = (blk - 400) * 256 + tid;
        if (i < WTBF_SHORTS) {
            int fidx = i >> 9, r = i & 511;
            int l = r >> 3, j = r & 7;
            int cg = fidx & 3, th = fidx >> 2;
            int tap = th >> 1, h = th & 1;
            int o = cg * 16 + (l & 15);
            int c = h * 32 + ((l >> 4) << 3) + j;
            ws[i] = f2h(w[o * 576 + c * 9 + tap]);
        }
        if (i < WTOFFF_SHORTS) {
            int fidx = i >> 9, r = i & 511;
            int l = r >> 3, j = r & 7;
            int g = fidx & 1, th = fidx >> 1;
            int tap = th >> 1, h = th & 1;
            int oc = g * 16 + (l & 15);
            int c = h * 32 + ((l >> 4) << 3) + j;
            float v = (oc < 18) ? w_off[oc * 576 + c * 9 + tap] : 0.f;
            ws[WTBF_SHORTS + i] = f2h(v);
        }
    } else {
        if (tid < 8)
            *(int4v*)((char*)(ws + XCL_OFS) + XCL_PIX * 128 + tid * 16) =
                (int4v){0, 0, 0, 0};
    }
}

// ---------------------------------------------------------------------------
// Sample NT taps, 4-deep corner-load pipeline; tables read from LDS;
// bilinear fully in packed fp16 (4 vector FMAs per 16B fragment).
// thread = (px = tid>>3, cg = tid&7), cb = cg*16 byte channel offset.
// ---------------------------------------------------------------------------
template<int T0, int NT>
__device__ __forceinline__ void sample_taps(const char* __restrict__ xclb,
                                            short (*__restrict__ sm)[32][72],
                                            const int4v (*__restrict__ linT)[9],
                                            const f16x4 (*__restrict__ wgtT)[9],
                                            int px, int cb) {
    int4v  liq[4];
    f16x4  wq[4];
    f16x8  stq[4][4];
    constexpr int PD = (NT < 4) ? NT : 4;
#pragma unroll
    for (int s = 0; s < PD; ++s) {
        liq[s] = linT[px][T0 + s];
        wq[s]  = wgtT[px][T0 + s];
#pragma unroll
        for (int c = 0; c < 4; ++c)
            stq[s][c] = *(const f16x8*)(xclb + liq[s][c] + cb);
    }
#pragma unroll
    for (int ti = 0; ti < NT; ++ti) {
        const int s = ti & 3;
        f16x8 a = stq[s][0] * vsplat(wq[s][0]) + stq[s][1] * vsplat(wq[s][1])
                + stq[s][2] * vsplat(wq[s][2]) + stq[s][3] * vsplat(wq[s][3]);
        *(f16x8*)((char*)&sm[ti][px][0] + cb) = a;
        if (ti + 4 < NT) {
            liq[s] = linT[px][T0 + ti + 4];
            wq[s]  = wgtT[px][T0 + ti + 4];
#pragma unroll
            for (int c = 0; c < 4; ++c)
                stq[s][c] = *(const f16x8*)(xclb + liq[s][c] + cb);
        }
        __builtin_amdgcn_sched_barrier(0);
    }
}

// ---------------------------------------------------------------------------
// GEMM NT taps from sm; fragment-major coalesced weight loads, 1-unit ahead.
// wfb = wTbF + nhalf*1024 + l*8 (shorts)
// ---------------------------------------------------------------------------
template<int T0, int NT>
__device__ __forceinline__ void gemm_taps(const short (*__restrict__ sm)[32][72],
                                          f32x4* acc, int px_t, int lg,
                                          const short* __restrict__ wfb) {
    f16x8 sa[2], s0[2], s1[2];
    sa[0] = *(const f16x8*)(&sm[0][px_t][lg * 8]);
    s0[0] = *(const f16x8*)(wfb + (T0 * 2) * 2048);
    s1[0] = *(const f16x8*)(wfb + (T0 * 2) * 2048 + 512);
#pragma unroll
    for (int u = 0; u < 2 * NT; ++u) {
        if (u + 1 < 2 * NT) {
            const int ti = (u + 1) >> 1, h = (u + 1) & 1, ns = (u + 1) & 1;
            sa[ns] = *(const f16x8*)(&sm[ti][px_t][h * 32 + lg * 8]);
            s0[ns] = *(const f16x8*)(wfb + ((T0 + ti) * 2 + h) * 2048);
            s1[ns] = *(const f16x8*)(wfb + ((T0 + ti) * 2 + h) * 2048 + 512);
        }
        __builtin_amdgcn_sched_barrier(0);
        const int cs = u & 1;
        acc[0] = __builtin_amdgcn_mfma_f32_16x16x32_f16(sa[cs], s0[cs], acc[0], 0, 0, 0);
        acc[1] = __builtin_amdgcn_mfma_f32_16x16x32_f16(sa[cs], s1[cs], acc[1], 0, 0, 0);
    }
}

// ---------------------------------------------------------------------------
// Fused kernel: 32-pixel tile; shared bilinear tables; fp16 datapath;
// 4-deep pipelined gathers; fragment-major weights.
// ---------------------------------------------------------------------------
__global__ __launch_bounds__(256, 4) void fused_cl(const short* __restrict__ ws,
                                                   const float* __restrict__ b_off,
                                                   const float* __restrict__ bias,
                                                   float* __restrict__ out) {
    __shared__ short sm[5][32][72];     // K-half im2col (fp16), padded rows
    __shared__ float offbuf[32][20];
    __shared__ int4v linT[32][9];       // byte offsets of 4 corners
    __shared__ f16x4 wgtT[32][9];       // bilinear weights, packed fp16

    int tid = threadIdx.x;
    int wid = tid >> 6;
    int l   = tid & 63;
    int lr  = l & 15;
    int lg  = l >> 4;
    int mhalf = wid >> 1;
    int nhalf = wid & 1;

    // XCD-aware swizzle: nwg = 3200, 3200 % 8 == 0 -> bijective
    int bid = blockIdx.x;
    int g_blk = (bid & 7) * 400 + (bid >> 3);

    int pix_base = g_blk * 32;
    int b   = pix_base / HWp;
    int rem = pix_base - b * HWp;
    int y   = rem / Ww;
    int x0  = rem - y * Ww;            // multiple of 32, row-aligned

    const short* wTbF   = ws;
    const short* wToffF = ws + WTBF_SHORTS;
    const char*  xclb   = (const char*)(ws + XCL_OFS) + (size_t)b * HWp * 128;
    const int zoff = (int)((Bq - b) * (size_t)HWp * 128);   // zero pad pixel

    // ---------------- Phase 1: offset GEMM (4-deep pipeline) --------------
    {
        int px_t1 = mhalf * 16 + lr;
        int xpix  = x0 + px_t1;
        int poff[9];
#pragma unroll
        for (int ty = 0; ty < 3; ++ty) {
#pragma unroll
            for (int tx = 0; tx < 3; ++tx) {
                int t  = ty * 3 + tx;
                int yy = y - 1 + ty;
                bool vy = (yy >= 0) && (yy < Hh);
                int yc = min(max(yy, 0), Hh - 1);
                int xx = xpix - 1 + tx;
                bool vx = (xx >= 0) && (xx < Ww);
                int xc = min(max(xx, 0), Ww - 1);
                poff[t] = (vy && vx) ? (yc * Ww + xc) * 128 : zoff;
            }
        }
        // B-frag base: frag (t,h,g=nhalf) at ((t*2+h)*2+nhalf)*512 + l*8
        const short* wofr = wToffF + (size_t)nhalf * 512 + l * 8;
        f32x4 accA = {0.f, 0.f, 0.f, 0.f};
        f32x4 accB = {0.f, 0.f, 0.f, 0.f};
        f16x8 sA[4], sB[4];
#pragma unroll
        for (int u = 0; u < 4; ++u) {
            const int t = u >> 1, h = u & 1;
            sA[u] = *(const f16x8*)(xclb + poff[t] + lg * 16 + h * 64);
            sB[u] = *(const f16x8*)(wofr + u * 1024);
        }
#pragma unroll
        for (int u = 0; u < 18; ++u) {
            const int s = u & 3;
            if (u & 1)
                accB = __builtin_amdgcn_mfma_f32_16x16x32_f16(sA[s], sB[s], accB, 0, 0, 0);
            else
                accA = __builtin_amdgcn_mfma_f32_16x16x32_f16(sA[s], sB[s], accA, 0, 0, 0);
            if (u + 4 < 18) {
                const int un = u + 4, t = un >> 1, h = un & 1;
                sA[s] = *(const f16x8*)(xclb + poff[t] + lg * 16 + h * 64);
                sB[s] = *(const f16x8*)(wofr + un * 1024);
            }
            __builtin_amdgcn_sched_barrier(0);
        }
        int oc_row = nhalf * 16 + lr;
        if (oc_row < 18) {
            float bv = b_off[oc_row];
#pragma unroll
            for (int j = 0; j < 4; ++j)
                offbuf[mhalf * 16 + lg * 4 + j][oc_row] = accA[j] + accB[j] + bv;
        }
    }
    __syncthreads();

    // ---------------- Phase 2: shared bilinear tables ----------------
    for (int i = tid; i < 288; i += 256) {
        int px = i / 9, tap = i - px * 9;
        int ty = tap / 3, tx = tap - ty * 3;
        f32x2 d2 = *(const f32x2*)&offbuf[px][2 * tap];
        float py  = (float)(y - 1 + ty) + d2[0];
        float pxf = (float)(x0 + px - 1 + tx) + d2[1];
        float fy = floorf(py), fx = floorf(pxf);
        float ly = py - fy, lx = pxf - fx;
        int iy0 = (int)fy, ix0 = (int)fx;
        int iy1 = iy0 + 1, ix1 = ix0 + 1;
        bool vy0 = (iy0 >= 0) && (iy0 < Hh);
        bool vy1 = (iy1 >= 0) && (iy1 < Hh);
        bool vx0 = (ix0 >= 0) && (ix0 < Ww);
        bool vx1 = (ix1 >= 0) && (ix1 < Ww);
        int cy0 = min(max(iy0, 0), Hh - 1), cy1 = min(max(iy1, 0), Hh - 1);
        int cx0 = min(max(ix0, 0), Ww - 1), cx1 = min(max(ix1, 0), Ww - 1);
        int4v li;
        li[0] = (cy0 * Ww + cx0) * 128;
        li[1] = (cy0 * Ww + cx1) * 128;
        li[2] = (cy1 * Ww + cx0) * 128;
        li[3] = (cy1 * Ww + cx1) * 128;
        float w00 = (vy0 && vx0) ? (1.f - ly) * (1.f - lx) : 0.f;
        float w01 = (vy0 && vx1) ? (1.f - ly) * lx         : 0.f;
        float w10 = (vy1 && vx0) ? ly * (1.f - lx)         : 0.f;
        float w11 = (vy1 && vx1) ? ly * lx                 : 0.f;
        linT[px][tap] = li;
        wgtT[px][tap] = (f16x4){(_Float16)w00, (_Float16)w01,
                                (_Float16)w10, (_Float16)w11};
    }
    __syncthreads();

    // ---------------- Sample + GEMM, two K-halves ----------
    int px = tid >> 3;          // 0..31
    int cg = tid & 7;
    int cb = cg * 16;

    f32x4 acc[2];
    acc[0] = (f32x4){0.f, 0.f, 0.f, 0.f};
    acc[1] = (f32x4){0.f, 0.f, 0.f, 0.f};
    int px_t = mhalf * 16 + lr;
    const short* wfb = wTbF + (size_t)nhalf * 1024 + l * 8;

    // half 0: taps 0..4
    sample_taps<0, 5>(xclb, sm, linT, wgtT, px, cb);
    __syncthreads();
    gemm_taps<0, 5>(sm, acc, px_t, lg, wfb);
    __syncthreads();

    // half 1: taps 5..8
    sample_taps<5, 4>(xclb, sm, linT, wgtT, px, cb);
    __syncthreads();
    gemm_taps<5, 4>(sm, acc, px_t, lg, wfb);

    // ---------------- Epilogue ----------------
    float* obase = out + (size_t)b * COUTc * HWp + y * Ww + x0;
#pragma unroll
    for (int nt = 0; nt < 2; ++nt) {
        int o = nhalf * 32 + nt * 16 + lr;
        float bv = bias[o];
#pragma unroll
        for (int j = 0; j < 4; ++j)
            obase[(size_t)o * HWp + mhalf * 16 + lg * 4 + j] = acc[nt][j] + bv;
    }
}

// ---------------------------------------------------------------------------
extern "C" void kernel_launch(void* const* d_in, const int* in_sizes, int n_in,
                              void* d_out, int out_size, void* d_ws, size_t ws_size,
                              hipStream_t stream) {
    const float* x      = (const float*)d_in[0];
    const float* w_off  = (const float*)d_in[1];
    const float* b_off  = (const float*)d_in[2];
    const float* weight = (const float*)d_in[3];
    const float* bias   = (const float*)d_in[4];
    float* outp = (float*)d_out;
    short* ws   = (short*)d_ws;

    // 400 blocks xcl + 144 blocks weights + 1 block zero pad
    prep_all<<<545, 256, 0, stream>>>(x, weight, w_off, ws);

    int nblocks = (Bq * HWp) / 32;   // 3200 workgroups, 32 pixels each
    fused_cl<<<nblocks, 256, 0, stream>>>(ws, b_off, bias, outp);
}